// Round 8
// baseline (87.889 us; speedup 1.0000x reference)
//
#include <hip/hip_runtime.h>
#include <hip/hip_bf16.h>

typedef __attribute__((ext_vector_type(4))) float f32x4;
typedef __attribute__((ext_vector_type(8))) short s16x8;

static constexpr int Bn = 32;
static constexpr int Tn = 4096;
static constexpr int Dn = 256;
static constexpr int Un = 256;
static constexpr int NBLK = 16;   // blocks per batch; block owns 256 t-rows = 8 chunks of 32

// fp32 -> bf16 round-to-nearest-even (software; used in prep only)
__device__ __forceinline__ ushort f2bf(float f) {
    unsigned x = __float_as_uint(f);
    x += 0x7fffu + ((x >> 16) & 1u);
    return (ushort)(x >> 16);
}

// HW packed fp32->bf16 (RTNE): dst = {lo16=bf16(a), hi16=bf16(b)}
__device__ __forceinline__ unsigned cvt_pk_bf16(float a, float b) {
    unsigned r;
    asm("v_cvt_pk_bf16_f32 %0, %1, %2" : "=v"(r) : "v"(a), "v"(b));
    return r;
}

// stable fast tanh: tanh(x) = sign(x) * (1 - e) / (1 + e), e = exp(-2|x|)
__device__ __forceinline__ float fast_tanh(float x) {
    float ax = fabsf(x);
    float e = __expf(-2.0f * ax);
    float r = __fdividef(1.0f - e, 1.0f + e);
    return copysignf(r, x);
}

__device__ __forceinline__ void gload_lds16(const void* g, void* l) {
    __builtin_amdgcn_global_load_lds(
        (const __attribute__((address_space(1))) unsigned*)g,
        (__attribute__((address_space(3))) unsigned*)l, 16, 0, 0);
}

// K0: fused prep. Blocks 0..255: W1T[u][d] = bf16(W1[d][u]).
// Blocks 256..287: qb[b][u] = query[b]·W2[:,u] + b1[u] + b2[u].
__global__ __launch_bounds__(256) void k_prep(const float* __restrict__ W1,
                                              ushort* __restrict__ W1T,
                                              const float* __restrict__ query,
                                              const float* __restrict__ W2,
                                              const float* __restrict__ b1,
                                              const float* __restrict__ b2,
                                              float* __restrict__ qb) {
    __shared__ float qs[Dn];
    if (blockIdx.x < 256) {
        const int u = blockIdx.x, d = threadIdx.x;
        W1T[u * Dn + d] = f2bf(W1[d * Un + u]);
    } else {
        const int b = blockIdx.x - 256, u = threadIdx.x;
        qs[u] = query[b * Dn + u];
        __syncthreads();
        float acc = b1[u] + b2[u];
        #pragma unroll 8
        for (int d = 0; d < Dn; ++d) acc += qs[d] * W2[d * Un + u];
        qb[b * Un + u] = acc;
    }
}

// K1: fused GEMM + flash. A staged as RAW FP32 via global_load_lds (no dest
// register -> compiler cannot sink it; vmcnt-tracked; issued one full chunk
// ahead, drained by the next top barrier = T3-minimum schedule). Content is
// row-XOR-swizzled (col_byte ^ (row&7)<<4) via pre-swizzled global source
// (LDS dest linear, rule 21 both-sides). In-loop fp32->bf16 via
// v_cvt_pk_bf16_f32. Context accumulates from the same fp32 tile.
__global__ __launch_bounds__(256, 2) void k_fused(const float* __restrict__ values,
                                                  const ushort* __restrict__ W1T,
                                                  const float* __restrict__ qb,
                                                  const float* __restrict__ Vw,
                                                  const float* __restrict__ bV,
                                                  float* __restrict__ scores,
                                                  float* __restrict__ pM,
                                                  float* __restrict__ pS,
                                                  float* __restrict__ pctx) {
    __shared__ __align__(16) float Afl[2][32][256];  // 64 KB dbuf, NO pad (gload_lds linear)
    __shared__ float sred[4][32];
    __shared__ float slp[32];
    __shared__ float sfac[2];
    __shared__ float runMS[2];
    __shared__ f32x4 cred[4][64];

    const int tid = threadIdx.x;
    const int b = blockIdx.y, blk = blockIdx.x;
    const int wid = tid >> 6, lane = tid & 63;
    const int l15 = lane & 15, hi = lane >> 4;

    const float* vbase = values + ((size_t)b * Tn + blk * 256) * Dn;
    const ushort* wbase = W1T + (size_t)(wid * 64 + l15) * Dn + hi * 8;

    float Vreg[4], qreg[4];
    #pragma unroll
    for (int ut = 0; ut < 4; ++ut) {
        int u = wid * 64 + ut * 16 + l15;
        Vreg[ut] = Vw[u];
        qreg[ut] = qb[b * Un + u];
    }
    const float bv = bV[0];

    if (tid == 0) { runMS[0] = -1e30f; runMS[1] = 0.f; }

    // stage chunk ck into Afl[buf]: one gload_lds per row (64 lanes x 16B = 1KB row);
    // per-lane global src pre-swizzled so LDS read with the same XOR is linear data.
    auto stage = [&](int ck, int buf) {
        const float* vc = vbase + (size_t)ck * 32 * Dn;
        #pragma unroll
        for (int j = 0; j < 8; ++j) {
            const int r = wid * 8 + j;
            const float* src = vc + (size_t)r * Dn + (((lane * 16) ^ ((r & 7) << 4)) >> 2);
            gload_lds16(src, &Afl[buf][r][0]);
        }
    };

    stage(0, 0);  // prologue: chunk 0 in flight

    f32x4 cacc = (f32x4){0.f, 0.f, 0.f, 0.f};

    #pragma unroll 1
    for (int ck = 0; ck < 8; ++ck) {
        const int cur = ck & 1;
        __syncthreads();  // B1: drains vmcnt -> Afl[cur] ready (also covers runMS init / prev context reads)

        if (ck < 7) stage(ck + 1, cur ^ 1);  // fire-and-forget; lands during this chunk's compute

        // B ring (depth-2, L2-hot W1T) + MFMA k-loop, zero barriers
        s16x8 bfn0[4], bfn1[4];
        #pragma unroll
        for (int ut = 0; ut < 4; ++ut)
            bfn0[ut] = *(const s16x8*)&wbase[(size_t)ut * 16 * Dn];
        #pragma unroll
        for (int ut = 0; ut < 4; ++ut)
            bfn1[ut] = *(const s16x8*)&wbase[(size_t)ut * 16 * Dn + 32];

        f32x4 acc[2][4];
        #pragma unroll
        for (int tt = 0; tt < 2; ++tt)
            #pragma unroll
            for (int ut = 0; ut < 4; ++ut) acc[tt][ut] = (f32x4){0.f, 0.f, 0.f, 0.f};

        #pragma unroll
        for (int kc = 0; kc < 8; ++kc) {
            s16x8 bf[4];
            #pragma unroll
            for (int ut = 0; ut < 4; ++ut) { bf[ut] = bfn0[ut]; bfn0[ut] = bfn1[ut]; }
            if (kc < 6) {
                #pragma unroll
                for (int ut = 0; ut < 4; ++ut)
                    bfn1[ut] = *(const s16x8*)&wbase[(size_t)ut * 16 * Dn + (kc + 2) * 32];
            }
            const int cbyte = kc * 128 + hi * 32;   // 8 consecutive fp32 = 2 x 16B
            #pragma unroll
            for (int tt = 0; tt < 2; ++tt) {
                const int r = tt * 16 + l15;
                const int xr = (r & 7) << 4;
                const float* pa = &Afl[cur][r][0];
                const f32x4 f0 = *(const f32x4*)(pa + ((cbyte ^ xr) >> 2));
                const f32x4 f1 = *(const f32x4*)(pa + (((cbyte + 16) ^ xr) >> 2));
                union { s16x8 v; unsigned u[4]; } af;
                af.u[0] = cvt_pk_bf16(f0[0], f0[1]);
                af.u[1] = cvt_pk_bf16(f0[2], f0[3]);
                af.u[2] = cvt_pk_bf16(f1[0], f1[1]);
                af.u[3] = cvt_pk_bf16(f1[2], f1[3]);
                #pragma unroll
                for (int ut = 0; ut < 4; ++ut)
                    acc[tt][ut] = __builtin_amdgcn_mfma_f32_16x16x32_bf16(af.v, bf[ut], acc[tt][ut], 0, 0, 0);
            }
        }

        // epilogue: tanh·V, reduce over u (16 lanes)
        float psc[2][4];
        #pragma unroll
        for (int tt = 0; tt < 2; ++tt)
            #pragma unroll
            for (int i = 0; i < 4; ++i) psc[tt][i] = 0.f;
        #pragma unroll
        for (int tt = 0; tt < 2; ++tt)
            #pragma unroll
            for (int ut = 0; ut < 4; ++ut)
                #pragma unroll
                for (int i = 0; i < 4; ++i)
                    psc[tt][i] += fast_tanh(acc[tt][ut][i] + qreg[ut]) * Vreg[ut];
        #pragma unroll
        for (int tt = 0; tt < 2; ++tt)
            #pragma unroll
            for (int i = 0; i < 4; ++i) {
                float v = psc[tt][i];
                v += __shfl_xor(v, 1, 64);
                v += __shfl_xor(v, 2, 64);
                v += __shfl_xor(v, 4, 64);
                v += __shfl_xor(v, 8, 64);
                if (l15 == 0) sred[wid][tt * 16 + hi * 4 + i] = v;
            }
        __syncthreads();  // B2

        // wave 0: scores + chunk softmax partials + running (M,S) update
        if (tid < 64) {
            const int row = lane & 31;
            float s = sred[0][row] + sred[1][row] + sred[2][row] + sred[3][row] + bv;
            if (lane < 32) scores[b * Tn + blk * 256 + ck * 32 + row] = s;
            float m = s;
            #pragma unroll
            for (int off = 16; off > 0; off >>= 1) m = fmaxf(m, __shfl_xor(m, off, 64));
            float p = __expf(s - m);
            float S = p;
            #pragma unroll
            for (int off = 16; off > 0; off >>= 1) S += __shfl_xor(S, off, 64);
            if (lane < 32) slp[row] = p;
            if (lane == 0) {
                float Mold = runMS[0];
                float Mnew = fmaxf(Mold, m);
                float sco = __expf(Mold - Mnew);
                float scc = __expf(m - Mnew);
                sfac[0] = sco; sfac[1] = scc;
                runMS[0] = Mnew;
                runMS[1] = runMS[1] * sco + S * scc;
            }
        }
        __syncthreads();  // B3

        // online context accumulation from the fp32 tile (swizzled reads)
        const float sco = sfac[0], scc = sfac[1];
        const int cb = (tid & 63) * 16;
        const int tg = tid >> 6;
        f32x4 loc = (f32x4){0.f, 0.f, 0.f, 0.f};
        #pragma unroll
        for (int t = tg; t < 32; t += 4) {
            const float p = slp[t];
            const float* pr = &Afl[cur][t][0];
            const f32x4 v = *(const f32x4*)(pr + ((cb ^ ((t & 7) << 4)) >> 2));
            loc[0] += p * v[0];
            loc[1] += p * v[1];
            loc[2] += p * v[2];
            loc[3] += p * v[3];
        }
        cacc = cacc * sco + loc * scc;
    }

    // block finalize: cross-tg context reduce + partials
    const int tg = tid >> 6;
    cred[tg][tid & 63] = cacc;
    __syncthreads();
    if (tg == 0) {
        const f32x4 o = cred[0][tid] + cred[1][tid] + cred[2][tid] + cred[3][tid];
        *(f32x4*)&pctx[((size_t)(b * NBLK + blk)) * Dn + (tid & 63) * 4] = o;
    }
    if (tid == 0) {
        pM[b * NBLK + blk] = runMS[0];
        pS[b * NBLK + blk] = runMS[1];
    }
}

// K2: per-batch flash reduce over NBLK block partials.
__global__ __launch_bounds__(256) void k_reduce(const float* __restrict__ pM,
                                                const float* __restrict__ pS,
                                                const float* __restrict__ pctx,
                                                float* __restrict__ context,
                                                float* __restrict__ MS) {
    const int b = blockIdx.x, d = threadIdx.x;
    float M = -1e30f;
    #pragma unroll
    for (int c = 0; c < NBLK; ++c) M = fmaxf(M, pM[b * NBLK + c]);
    float S = 0.f, ctx = 0.f;
    #pragma unroll
    for (int c = 0; c < NBLK; ++c) {
        const float w = __expf(pM[b * NBLK + c] - M);
        S += w * pS[b * NBLK + c];
        ctx += w * pctx[((size_t)(b * NBLK + c)) * Dn + d];
    }
    context[b * Dn + d] = __fdividef(ctx, S);
    if (d == 0) { MS[b * 2] = M; MS[b * 2 + 1] = S; }
}

// K3: attn[b,t] = exp(score - M_b) / S_b, in place over the score buffer.
__global__ __launch_bounds__(256) void k_attn(float* __restrict__ attn,
                                              const float* __restrict__ MS) {
    const int b = blockIdx.y;
    const int base = b * Tn + blockIdx.x * 1024 + threadIdx.x * 4;
    const float M = MS[b * 2];
    const float invS = __fdividef(1.0f, MS[b * 2 + 1]);
    float4 s = *(const float4*)&attn[base];
    s.x = __expf(s.x - M) * invS;
    s.y = __expf(s.y - M) * invS;
    s.z = __expf(s.z - M) * invS;
    s.w = __expf(s.w - M) * invS;
    *(float4*)&attn[base] = s;
}

extern "C" void kernel_launch(void* const* d_in, const int* in_sizes, int n_in,
                              void* d_out, int out_size, void* d_ws, size_t ws_size,
                              hipStream_t stream) {
    const float* query  = (const float*)d_in[0];
    const float* values = (const float*)d_in[1];
    const float* W1     = (const float*)d_in[2];
    const float* b1     = (const float*)d_in[3];
    const float* W2     = (const float*)d_in[4];
    const float* b2     = (const float*)d_in[5];
    const float* Vw     = (const float*)d_in[6];
    const float* bV     = (const float*)d_in[7];

    float* context = (float*)d_out;            // [B,D]
    float* attn    = (float*)d_out + Bn * Dn;  // [B,T,1] — raw scores, then attn in place

    float*  pctx = (float*)d_ws;                       // [B, NBLK, D]
    float*  pM   = pctx + (size_t)Bn * NBLK * Dn;      // [B, NBLK]
    float*  pS   = pM + Bn * NBLK;                     // [B, NBLK]
    float*  qb   = pS + Bn * NBLK;                     // [B, U]
    float*  MS   = qb + Bn * Un;                       // [B, 2]
    ushort* W1T  = (ushort*)(MS + Bn * 2);             // [U, D] bf16

    k_prep<<<dim3(256 + Bn), dim3(256), 0, stream>>>(W1, W1T, query, W2, b1, b2, qb);
    k_fused<<<dim3(NBLK, Bn), dim3(256), 0, stream>>>(values, W1T, qb, Vw, bV,
                                                      attn, pM, pS, pctx);
    k_reduce<<<dim3(Bn), dim3(256), 0, stream>>>(pM, pS, pctx, context, MS);
    k_attn<<<dim3(Tn / 1024, Bn), dim3(256), 0, stream>>>(attn, MS);
}